// Round 2
// baseline (2685.725 us; speedup 1.0000x reference)
//
#include <hip/hip_runtime.h>
#include <cstddef>

#define T_LEN 50000

__device__ __forceinline__ float sp_(float x){ return (x > 20.f) ? x : log1pf(expf(x)); }
__device__ __forceinline__ float gelu1(float x){ return 0.5f*x*(1.f + erff(x*0.7071067811865475f)); }

// ---------------- kernel 0: transpose w_proj [d][i] -> wT [i][d] ----------------
__global__ void k_transpose(const float* __restrict__ wproj, float* __restrict__ wT)
{
    int idx = blockIdx.x*256 + threadIdx.x;
    if (idx < 16000) {
        int d = idx / 100, i = idx % 100;
        wT[i*160 + d] = wproj[idx];
    }
}

// ---------------- kernel 1: preprocessing chain -> xs (B,4,T) + m_patch ----------------
// block: 256 threads, tile = 1000 t (40 patches). grid = 64*50.
__global__ __launch_bounds__(256) void k_pre(
    const float* __restrict__ X, const float* __restrict__ Mq,
    const float* __restrict__ w_env, const float* __restrict__ w_bur,
    const float* __restrict__ syn, const float* __restrict__ wdw,
    const float* __restrict__ wpw,
    float* __restrict__ xs_out, float* __restrict__ mpatch)
{
    // padded addressing: logical idx i -> physical i + (i>>2)  (breaks 64B-stride b128 conflicts)
    __shared__ float4 xb[1290];    // x tile, t in [t0-16, t0+1016), channel-packed
    __shared__ float4 s1b[1260];   // S1 tile, t in [t0-4, t0+1004)
    __shared__ unsigned char maskb[1032];
    __shared__ float WnL[16];
    __shared__ float4 SmLUT[16];

    const int tid  = threadIdx.x;
    const int b    = blockIdx.x / 50;
    const int tile = blockIdx.x % 50;
    const int t0   = tile * 1000;

    // ---- phase 1: load x = X*M (float4 over channels), build mask ----
    const float4* X4 = (const float4*)X + (size_t)b * T_LEN;
    const float4* M4 = (const float4*)Mq + (size_t)b * T_LEN;
    #pragma unroll
    for (int jj = 0; jj < 5; ++jj) {
        int idx = tid + jj*256;
        if (idx < 1032) {
            int t = t0 - 16 + idx;
            float4 xv = make_float4(0.f,0.f,0.f,0.f);
            unsigned mk = 0u;
            if (t >= 0 && t < T_LEN) {
                float4 a = X4[t], m = M4[t];
                xv = make_float4(a.x*m.x, a.y*m.y, a.z*m.z, a.w*m.w);
                mk = (m.x>0.f?1u:0u) | (m.y>0.f?2u:0u) | (m.z>0.f?4u:0u) | (m.w>0.f?8u:0u);
            }
            xb[idx + (idx>>2)] = xv;
            maskb[idx] = (unsigned char)mk;
        }
    }
    if (tid < 4) {  // normalized softplus synergy row
        float w0 = sp_(syn[tid*4+0]), w1 = sp_(syn[tid*4+1]);
        float w2 = sp_(syn[tid*4+2]), w3 = sp_(syn[tid*4+3]);
        float inv = 1.f / fmaxf(w0+w1+w2+w3, 1e-6f);
        WnL[tid*4+0]=w0*inv; WnL[tid*4+1]=w1*inv; WnL[tid*4+2]=w2*inv; WnL[tid*4+3]=w3*inv;
    }
    __syncthreads();
    if (tid < 16) {  // Sm lookup by 4-bit channel mask
        float sm[4];
        #pragma unroll
        for (int m=0;m<4;++m) {
            float a = 0.f;
            #pragma unroll
            for (int c=0;c<4;++c) if (tid & (1<<c)) a += WnL[m*4+c];
            sm[m] = fminf(a, 1.f);
        }
        SmLUT[tid] = make_float4(sm[0],sm[1],sm[2],sm[3]);
    }

    // ---- phase 2: env/burst/xm -> S1 for t in [t0-4, t0+1004), run of 4 per thread ----
    if (tid < 252) {
        float4 env[4], bur[4], xk[4];
        #pragma unroll
        for (int j=0;j<4;++j){ env[j]=make_float4(0,0,0,0); bur[j]=make_float4(0,0,0,0); }
        float4 xprev = make_float4(0,0,0,0);
        const int base  = 4*tid;          // lt of window start (τ0-12)
        const int gbase = t0 - 4 + 4*tid; // global τ0
        #pragma unroll
        for (int s = -12; s <= 15; ++s) {
            int lt = base + (s+12);
            float4 xc = xb[lt + (lt>>2)];
            float4 ax = make_float4(fabsf(xc.x),fabsf(xc.y),fabsf(xc.z),fabsf(xc.w));
            if (s >= -4 && s <= 7) {      // dx contributions
                int g = gbase + s;
                float4 dx;
                // reference: dx defined on [0,T) with dx[0]=0; conv zero-pads outside.
                // g==T_LEN would otherwise give 0 - x[T-1] != 0  (R1 bugfix)
                if (g <= 0 || g >= T_LEN) dx = make_float4(0,0,0,0);
                else dx = make_float4(xc.x-xprev.x, xc.y-xprev.y, xc.z-xprev.z, xc.w-xprev.w);
                float4 adx = make_float4(fabsf(dx.x),fabsf(dx.y),fabsf(dx.z),fabsf(dx.w));
                #pragma unroll
                for (int j=0;j<4;++j) {
                    int bk = s + 4 - j;
                    if (bk >= 0 && bk < 9) {
                        float b0=w_bur[bk], b1=w_bur[9+bk], b2=w_bur[18+bk], b3=w_bur[27+bk];
                        bur[j].x = fmaf(b0, adx.x, bur[j].x);
                        bur[j].y = fmaf(b1, adx.y, bur[j].y);
                        bur[j].z = fmaf(b2, adx.z, bur[j].z);
                        bur[j].w = fmaf(b3, adx.w, bur[j].w);
                    }
                }
            }
            #pragma unroll
            for (int j=0;j<4;++j) {
                int k = s + 12 - j;
                if (k >= 0 && k < 25) {
                    float e0=w_env[k], e1=w_env[25+k], e2=w_env[50+k], e3=w_env[75+k];
                    env[j].x = fmaf(e0, ax.x, env[j].x);
                    env[j].y = fmaf(e1, ax.y, env[j].y);
                    env[j].z = fmaf(e2, ax.z, env[j].z);
                    env[j].w = fmaf(e3, ax.w, env[j].w);
                }
            }
            if (s >= 0 && s <= 3) xk[s] = xc;
            xprev = xc;
        }
        #pragma unroll
        for (int j=0;j<4;++j) {
            int g = gbase + j;
            float4 xm = make_float4(
                0.9f*env[j].x + 0.6f*bur[j].x + 0.2f*xk[j].x,
                0.9f*env[j].y + 0.6f*bur[j].y + 0.2f*xk[j].y,
                0.9f*env[j].z + 0.6f*bur[j].z + 0.2f*xk[j].z,
                0.9f*env[j].w + 0.6f*bur[j].w + 0.2f*xk[j].w);
            float4 out = make_float4(0,0,0,0);
            if (g >= 0 && g < T_LEN) {
                out.x = WnL[0]*xm.x  + WnL[1]*xm.y  + WnL[2]*xm.z  + WnL[3]*xm.w;
                out.y = WnL[4]*xm.x  + WnL[5]*xm.y  + WnL[6]*xm.z  + WnL[7]*xm.w;
                out.z = WnL[8]*xm.x  + WnL[9]*xm.y  + WnL[10]*xm.z + WnL[11]*xm.w;
                out.w = WnL[12]*xm.x + WnL[13]*xm.y + WnL[14]*xm.z + WnL[15]*xm.w;
            }
            int ls = base + j;   // ls = τ - (t0-4)
            s1b[ls + (ls>>2)] = out;
        }
    }
    __syncthreads();

    // ---- phase 3: pre-dw conv + gelu + pw + gelu, * Sm -> xs; m_time ----
    if (tid < 250) {
        float4 s2a[4];
        #pragma unroll
        for (int j=0;j<4;++j) s2a[j]=make_float4(0,0,0,0);
        const int base = 4*tid;   // τ0' - t0
        #pragma unroll
        for (int s = -4; s <= 7; ++s) {
            int ls = base + s + 4;
            float4 sc = s1b[ls + (ls>>2)];
            #pragma unroll
            for (int j=0;j<4;++j) {
                int k = s + 4 - j;
                if (k >= 0 && k < 9) {
                    float d0=wdw[k], d1=wdw[9+k], d2=wdw[18+k], d3=wdw[27+k];
                    s2a[j].x = fmaf(d0, sc.x, s2a[j].x);
                    s2a[j].y = fmaf(d1, sc.y, s2a[j].y);
                    s2a[j].z = fmaf(d2, sc.z, s2a[j].z);
                    s2a[j].w = fmaf(d3, sc.w, s2a[j].w);
                }
            }
        }
        float xsv[4][4];
        float mt[4];
        #pragma unroll
        for (int j=0;j<4;++j) {
            float g0 = gelu1(s2a[j].x), g1 = gelu1(s2a[j].y);
            float g2 = gelu1(s2a[j].z), g3 = gelu1(s2a[j].w);
            float4 sm = SmLUT[maskb[base + j + 16]];
            float s3o[4];
            #pragma unroll
            for (int o=0;o<4;++o) {
                float v = wpw[o*4+0]*g0 + wpw[o*4+1]*g1 + wpw[o*4+2]*g2 + wpw[o*4+3]*g3;
                s3o[o] = gelu1(v);
            }
            xsv[j][0]=s3o[0]*sm.x; xsv[j][1]=s3o[1]*sm.y;
            xsv[j][2]=s3o[2]*sm.z; xsv[j][3]=s3o[3]*sm.w;
            mt[j] = sm.x + sm.y + sm.z + sm.w;
        }
        #pragma unroll
        for (int m=0;m<4;++m) {
            float4 st = make_float4(xsv[0][m], xsv[1][m], xsv[2][m], xsv[3][m]);
            *(float4*)(xs_out + (size_t)(b*4+m)*T_LEN + t0 + base) = st;
        }
        float* mtb = (float*)xb;   // xb dead after phase 2
        mtb[base+0]=mt[0]; mtb[base+1]=mt[1]; mtb[base+2]=mt[2]; mtb[base+3]=mt[3];
    }
    __syncthreads();

    // ---- phase 4: m_patch per 25-t patch ----
    if (tid < 40) {
        const float* mtb = (const float*)xb;
        int cnt = 0;
        #pragma unroll
        for (int k=0;k<25;++k) cnt += (mtb[tid*25+k] > 0.f) ? 1 : 0;
        mpatch[(size_t)b*2000 + tile*40 + tid] = (cnt >= 3) ? 1.f : 0.f;
    }
}

// ---------------- kernel 2: patch projection (K=100 -> D=160) + LayerNorm ----------------
// block: 192 threads (3 waves), d = tid; 32 patches/block in 4 batches of 8.
__global__ __launch_bounds__(192) void k_proj(
    const float* __restrict__ wT, const float* __restrict__ xs,
    const float* __restrict__ gamma, const float* __restrict__ beta,
    float* __restrict__ hout)
{
    __shared__ float xsb[800];        // 8 patches x 100 (i = m*25+k)
    __shared__ float red[3][8][2];
    const int tid  = threadIdx.x;
    const int d    = tid;
    const int wv   = tid >> 6;
    const int lane = tid & 63;
    const bool act = (d < 160);

    float wreg[100];
    #pragma unroll
    for (int i=0;i<100;++i) wreg[i] = act ? wT[i*160 + d] : 0.f;
    const float gam = act ? gamma[d] : 0.f;
    const float bet = act ? beta[d]  : 0.f;

    const int pbase = blockIdx.x * 32;
    for (int bt = 0; bt < 4; ++bt) {
        const int p0 = pbase + bt*8;
        const int b  = p0 / 2000;
        const int l0 = p0 % 2000;
        __syncthreads();   // protect xsb/red reuse
        #pragma unroll
        for (int jj=0;jj<5;++jj) {
            int idx = tid + jj*192;
            if (idx < 800) {
                int m = idx / 200, j = idx % 200;
                float v = xs[(size_t)(b*4+m)*T_LEN + l0*25 + j];
                xsb[(j/25)*100 + m*25 + (j%25)] = v;
            }
        }
        __syncthreads();

        float acc[8];
        #pragma unroll
        for (int p=0;p<8;++p) acc[p]=0.f;
        #pragma unroll
        for (int p=0;p<8;++p) {
            const float4* xp = (const float4*)(xsb + p*100);
            #pragma unroll
            for (int i4=0;i4<25;++i4) {
                float4 v = xp[i4];   // same-address broadcast across the wave
                acc[p] = fmaf(wreg[i4*4+0], v.x, acc[p]);
                acc[p] = fmaf(wreg[i4*4+1], v.y, acc[p]);
                acc[p] = fmaf(wreg[i4*4+2], v.z, acc[p]);
                acc[p] = fmaf(wreg[i4*4+3], v.w, acc[p]);
            }
        }
        // ---- LayerNorm, two-pass variance (mean first, then squared deviations) ----
        // pass 1: mean
        #pragma unroll
        for (int p=0;p<8;++p) {
            float a = acc[p];
            #pragma unroll
            for (int off=32; off>0; off>>=1) a += __shfl_xor(a, off, 64);
            if (lane == 0) { red[wv][p][0] = a; }
        }
        __syncthreads();
        float mu[8];
        #pragma unroll
        for (int p=0;p<8;++p)
            mu[p] = (red[0][p][0] + red[1][p][0] + red[2][p][0]) * (1.f/160.f);
        __syncthreads();
        // pass 2: sum of squared deviations (numerically matches np two-pass var)
        #pragma unroll
        for (int p=0;p<8;++p) {
            float dv = act ? (acc[p] - mu[p]) : 0.f;
            float q = dv*dv;
            #pragma unroll
            for (int off=32; off>0; off>>=1) q += __shfl_xor(q, off, 64);
            if (lane == 0) { red[wv][p][1] = q; }
        }
        __syncthreads();
        #pragma unroll
        for (int p=0;p<8;++p) {
            float Q = red[0][p][1] + red[1][p][1] + red[2][p][1];
            float var = Q * (1.f/160.f);
            float rs  = rsqrtf(var + 1e-5f);
            if (act) hout[((size_t)b*2000 + l0 + p)*160 + d] = (acc[p]-mu[p])*rs*gam + bet;
        }
    }
}

extern "C" void kernel_launch(void* const* d_in, const int* in_sizes, int n_in,
                              void* d_out, int out_size, void* d_ws, size_t ws_size,
                              hipStream_t stream) {
    const float* X     = (const float*)d_in[0];
    const float* M     = (const float*)d_in[1];
    const float* w_env = (const float*)d_in[2];
    const float* w_bur = (const float*)d_in[3];
    const float* syn   = (const float*)d_in[4];
    const float* wdw   = (const float*)d_in[5];
    const float* wpw   = (const float*)d_in[6];
    const float* wproj = (const float*)d_in[7];
    const float* gam   = (const float*)d_in[8];
    const float* bet   = (const float*)d_in[9];

    float* h      = (float*)d_out;                       // (64,2000,160)
    float* mpatch = h + (size_t)64*2000*160;             // (64,2000)

    float* wT = (float*)d_ws;                            // 64 KB
    float* xs = (float*)((char*)d_ws + 65536);           // (64,4,50000) = 51.2 MB

    k_transpose<<<63, 256, 0, stream>>>(wproj, wT);
    k_pre<<<3200, 256, 0, stream>>>(X, M, w_env, w_bur, syn, wdw, wpw, xs, mpatch);
    k_proj<<<4000, 192, 0, stream>>>(wT, xs, gam, bet, h);
}

// Round 3
// 256.594 us; speedup vs baseline: 10.4668x; 10.4668x over previous
//
#include <hip/hip_runtime.h>
#include <hip/hip_bf16.h>
#include <cstddef>

#define T_LEN 50000

typedef __attribute__((ext_vector_type(8))) short bf16x8;
typedef __attribute__((ext_vector_type(4))) float f32x4;

__device__ __forceinline__ float sp_(float x){ return (x > 20.f) ? x : log1pf(expf(x)); }
__device__ __forceinline__ float gelu1(float x){ return 0.5f*x*(1.f + erff(x*0.7071067811865475f)); }

// ---------------- kernel 0: w_proj [160][100] fp32 -> wbf [160][128] bf16 (K zero-padded) ----
__global__ void k_cvtw(const float* __restrict__ wproj, __hip_bfloat16* __restrict__ wbf)
{
    int idx = blockIdx.x*256 + threadIdx.x;
    if (idx < 160*128) {
        int d = idx >> 7, i = idx & 127;
        float v = (i < 100) ? wproj[d*100 + i] : 0.f;
        wbf[idx] = __float2bfloat16(v);
    }
}

// ---------------- kernel 1: preprocessing chain -> xs bf16 [patch][128] + m_patch ----------
// block: 256 threads, tile = 1000 t (40 patches). grid = 64*50.
__global__ __launch_bounds__(256) void k_pre(
    const float* __restrict__ X, const float* __restrict__ Mq,
    const float* __restrict__ w_env, const float* __restrict__ w_bur,
    const float* __restrict__ syn, const float* __restrict__ wdw,
    const float* __restrict__ wpw,
    __hip_bfloat16* __restrict__ xs_out, float* __restrict__ mpatch)
{
    __shared__ float4 xb[1290];    // x tile, t in [t0-16, t0+1016), +1-per-4 padded
    __shared__ float4 s1b[1260];   // S1 tile, t in [t0-4, t0+1004)
    __shared__ unsigned char maskb[1032];
    __shared__ float WnL[16];
    __shared__ float4 SmLUT[16];
    __shared__ __align__(16) __hip_bfloat16 abf[40*128];  // A-layout tile: [patch][i=m*25+k]
    __shared__ float mtL[1000];

    const int tid  = threadIdx.x;
    const int b    = blockIdx.x / 50;
    const int tile = blockIdx.x % 50;
    const int t0   = tile * 1000;

    // ---- phase 1: load x = X*M (float4 over channels), build mask; zero abf K-pad ----
    const float4* X4 = (const float4*)X + (size_t)b * T_LEN;
    const float4* M4 = (const float4*)Mq + (size_t)b * T_LEN;
    #pragma unroll
    for (int jj = 0; jj < 5; ++jj) {
        int idx = tid + jj*256;
        if (idx < 1032) {
            int t = t0 - 16 + idx;
            float4 xv = make_float4(0.f,0.f,0.f,0.f);
            unsigned mk = 0u;
            if (t >= 0 && t < T_LEN) {
                float4 a = X4[t], m = M4[t];
                xv = make_float4(a.x*m.x, a.y*m.y, a.z*m.z, a.w*m.w);
                mk = (m.x>0.f?1u:0u) | (m.y>0.f?2u:0u) | (m.z>0.f?4u:0u) | (m.w>0.f?8u:0u);
            }
            xb[idx + (idx>>2)] = xv;
            maskb[idx] = (unsigned char)mk;
        }
    }
    for (int idx = tid; idx < 40*28; idx += 256) {   // zero i in [100,128)
        int p = idx / 28, i = 100 + idx % 28;
        abf[p*128 + i] = __float2bfloat16(0.f);
    }
    if (tid < 4) {
        float w0 = sp_(syn[tid*4+0]), w1 = sp_(syn[tid*4+1]);
        float w2 = sp_(syn[tid*4+2]), w3 = sp_(syn[tid*4+3]);
        float inv = 1.f / fmaxf(w0+w1+w2+w3, 1e-6f);
        WnL[tid*4+0]=w0*inv; WnL[tid*4+1]=w1*inv; WnL[tid*4+2]=w2*inv; WnL[tid*4+3]=w3*inv;
    }
    __syncthreads();
    if (tid < 16) {
        float sm[4];
        #pragma unroll
        for (int m=0;m<4;++m) {
            float a = 0.f;
            #pragma unroll
            for (int c=0;c<4;++c) if (tid & (1<<c)) a += WnL[m*4+c];
            sm[m] = fminf(a, 1.f);
        }
        SmLUT[tid] = make_float4(sm[0],sm[1],sm[2],sm[3]);
    }

    // ---- phase 2: env/burst/xm -> S1 for t in [t0-4, t0+1004) ----
    if (tid < 252) {
        float4 env[4], bur[4], xk[4];
        #pragma unroll
        for (int j=0;j<4;++j){ env[j]=make_float4(0,0,0,0); bur[j]=make_float4(0,0,0,0); }
        float4 xprev = make_float4(0,0,0,0);
        const int base  = 4*tid;
        const int gbase = t0 - 4 + 4*tid;
        #pragma unroll
        for (int s = -12; s <= 15; ++s) {
            int lt = base + (s+12);
            float4 xc = xb[lt + (lt>>2)];
            float4 ax = make_float4(fabsf(xc.x),fabsf(xc.y),fabsf(xc.z),fabsf(xc.w));
            if (s >= -4 && s <= 7) {
                int g = gbase + s;
                float4 dx;
                if (g <= 0 || g >= T_LEN) dx = make_float4(0,0,0,0);
                else dx = make_float4(xc.x-xprev.x, xc.y-xprev.y, xc.z-xprev.z, xc.w-xprev.w);
                float4 adx = make_float4(fabsf(dx.x),fabsf(dx.y),fabsf(dx.z),fabsf(dx.w));
                #pragma unroll
                for (int j=0;j<4;++j) {
                    int bk = s + 4 - j;
                    if (bk >= 0 && bk < 9) {
                        float b0=w_bur[bk], b1=w_bur[9+bk], b2=w_bur[18+bk], b3=w_bur[27+bk];
                        bur[j].x = fmaf(b0, adx.x, bur[j].x);
                        bur[j].y = fmaf(b1, adx.y, bur[j].y);
                        bur[j].z = fmaf(b2, adx.z, bur[j].z);
                        bur[j].w = fmaf(b3, adx.w, bur[j].w);
                    }
                }
            }
            #pragma unroll
            for (int j=0;j<4;++j) {
                int k = s + 12 - j;
                if (k >= 0 && k < 25) {
                    float e0=w_env[k], e1=w_env[25+k], e2=w_env[50+k], e3=w_env[75+k];
                    env[j].x = fmaf(e0, ax.x, env[j].x);
                    env[j].y = fmaf(e1, ax.y, env[j].y);
                    env[j].z = fmaf(e2, ax.z, env[j].z);
                    env[j].w = fmaf(e3, ax.w, env[j].w);
                }
            }
            if (s >= 0 && s <= 3) xk[s] = xc;
            xprev = xc;
        }
        #pragma unroll
        for (int j=0;j<4;++j) {
            int g = gbase + j;
            float4 xm = make_float4(
                0.9f*env[j].x + 0.6f*bur[j].x + 0.2f*xk[j].x,
                0.9f*env[j].y + 0.6f*bur[j].y + 0.2f*xk[j].y,
                0.9f*env[j].z + 0.6f*bur[j].z + 0.2f*xk[j].z,
                0.9f*env[j].w + 0.6f*bur[j].w + 0.2f*xk[j].w);
            float4 out = make_float4(0,0,0,0);
            if (g >= 0 && g < T_LEN) {
                out.x = WnL[0]*xm.x  + WnL[1]*xm.y  + WnL[2]*xm.z  + WnL[3]*xm.w;
                out.y = WnL[4]*xm.x  + WnL[5]*xm.y  + WnL[6]*xm.z  + WnL[7]*xm.w;
                out.z = WnL[8]*xm.x  + WnL[9]*xm.y  + WnL[10]*xm.z + WnL[11]*xm.w;
                out.w = WnL[12]*xm.x + WnL[13]*xm.y + WnL[14]*xm.z + WnL[15]*xm.w;
            }
            int ls = base + j;
            s1b[ls + (ls>>2)] = out;
        }
    }
    __syncthreads();

    // ---- phase 3: pre-dw + gelu + pw + gelu, * Sm -> abf (bf16, A-layout); mtL ----
    if (tid < 250) {
        float4 s2a[4];
        #pragma unroll
        for (int j=0;j<4;++j) s2a[j]=make_float4(0,0,0,0);
        const int base = 4*tid;
        #pragma unroll
        for (int s = -4; s <= 7; ++s) {
            int ls = base + s + 4;
            float4 sc = s1b[ls + (ls>>2)];
            #pragma unroll
            for (int j=0;j<4;++j) {
                int k = s + 4 - j;
                if (k >= 0 && k < 9) {
                    float d0=wdw[k], d1=wdw[9+k], d2=wdw[18+k], d3=wdw[27+k];
                    s2a[j].x = fmaf(d0, sc.x, s2a[j].x);
                    s2a[j].y = fmaf(d1, sc.y, s2a[j].y);
                    s2a[j].z = fmaf(d2, sc.z, s2a[j].z);
                    s2a[j].w = fmaf(d3, sc.w, s2a[j].w);
                }
            }
        }
        #pragma unroll
        for (int j=0;j<4;++j) {
            int t = base + j;              // local t in [0,1000)
            float g0 = gelu1(s2a[j].x), g1 = gelu1(s2a[j].y);
            float g2 = gelu1(s2a[j].z), g3 = gelu1(s2a[j].w);
            float4 sm = SmLUT[maskb[t + 16]];
            int p = t / 25, k = t % 25;
            float smv[4] = {sm.x, sm.y, sm.z, sm.w};
            #pragma unroll
            for (int o=0;o<4;++o) {
                float v = wpw[o*4+0]*g0 + wpw[o*4+1]*g1 + wpw[o*4+2]*g2 + wpw[o*4+3]*g3;
                abf[p*128 + o*25 + k] = __float2bfloat16(gelu1(v) * smv[o]);
            }
            mtL[t] = sm.x + sm.y + sm.z + sm.w;
        }
    }
    __syncthreads();

    // ---- phase 4: copy abf -> global (coalesced), m_patch ----
    {
        const float4* src = (const float4*)abf;
        float4* dst = (float4*)(xs_out + (size_t)(b*2000 + tile*40)*128);
        #pragma unroll
        for (int it = 0; it < 3; ++it) {
            int idx = tid + it*256;
            if (idx < 640) dst[idx] = src[idx];
        }
    }
    if (tid < 40) {
        int cnt = 0;
        #pragma unroll
        for (int k=0;k<25;++k) cnt += (mtL[tid*25+k] > 0.f) ? 1 : 0;
        mpatch[(size_t)b*2000 + tile*40 + tid] = (cnt >= 3) ? 1.f : 0.f;
    }
}

// ---------------- kernel 2: MFMA patch projection (M=128000, N=160, K=128) + LayerNorm ----
// block 256 (4 waves); per batch: 64 patches; each wave: 16 patches x 160 d; 2 batches/block.
__global__ __launch_bounds__(256) void k_proj(
    const __hip_bfloat16* __restrict__ wbf, const __hip_bfloat16* __restrict__ xsg,
    const float* __restrict__ gamma, const float* __restrict__ beta,
    float* __restrict__ hout)
{
    __shared__ __align__(16) unsigned short Wl[160*136];  // [d][K=128 pad 136]
    __shared__ __align__(16) unsigned short Al[64*136];   // [patch][K=128 pad 136]
    const int tid  = threadIdx.x;
    const int wv   = tid >> 6, lane = tid & 63;
    const int n    = lane & 15, quad = lane >> 4;

    // stage W (row-major d, padded): 160 rows x 16 chunks of 16B
    {
        const float4* wg = (const float4*)wbf;
        #pragma unroll
        for (int it = 0; it < 10; ++it) {
            int idx = tid + it*256;
            int row = idx >> 4, cir = idx & 15;
            *(float4*)(Wl + row*136 + cir*8) = wg[idx];
        }
    }
    float gm[10], bt_[10];
    #pragma unroll
    for (int t = 0; t < 10; ++t) { gm[t] = gamma[t*16 + n]; bt_[t] = beta[t*16 + n]; }

    for (int bt = 0; bt < 2; ++bt) {
        const int p0 = (blockIdx.x*2 + bt) * 64;
        __syncthreads();
        {
            const float4* ag = (const float4*)(xsg + (size_t)p0*128);
            #pragma unroll
            for (int it = 0; it < 4; ++it) {
                int idx = tid + it*256;
                int row = idx >> 4, cir = idx & 15;
                *(float4*)(Al + row*136 + cir*8) = ag[idx];
            }
        }
        __syncthreads();

        f32x4 acc[10];
        #pragma unroll
        for (int t = 0; t < 10; ++t) acc[t] = (f32x4){0.f,0.f,0.f,0.f};
        #pragma unroll
        for (int kk = 0; kk < 4; ++kk) {
            bf16x8 af = *(const bf16x8*)(Al + (wv*16 + n)*136 + kk*32 + quad*8);
            #pragma unroll
            for (int t = 0; t < 10; ++t) {
                bf16x8 bf = *(const bf16x8*)(Wl + (t*16 + n)*136 + kk*32 + quad*8);
                acc[t] = __builtin_amdgcn_mfma_f32_16x16x32_bf16(af, bf, acc[t], 0, 0, 0);
            }
        }

        // LayerNorm in registers: C/D layout row(patch)=quad*4+r, col(d)=t*16+n
        float mu[4], rs[4];
        #pragma unroll
        for (int r = 0; r < 4; ++r) {
            float a = 0.f;
            #pragma unroll
            for (int t = 0; t < 10; ++t) a += acc[t][r];
            a += __shfl_xor(a, 1, 64); a += __shfl_xor(a, 2, 64);
            a += __shfl_xor(a, 4, 64); a += __shfl_xor(a, 8, 64);
            mu[r] = a * (1.f/160.f);
        }
        #pragma unroll
        for (int r = 0; r < 4; ++r) {
            float q = 0.f;
            #pragma unroll
            for (int t = 0; t < 10; ++t) { float dv = acc[t][r] - mu[r]; q = fmaf(dv, dv, q); }
            q += __shfl_xor(q, 1, 64); q += __shfl_xor(q, 2, 64);
            q += __shfl_xor(q, 4, 64); q += __shfl_xor(q, 8, 64);
            rs[r] = rsqrtf(q * (1.f/160.f) + 1e-5f);
        }
        const int prow = p0 + wv*16 + quad*4;
        #pragma unroll
        for (int t = 0; t < 10; ++t) {
            #pragma unroll
            for (int r = 0; r < 4; ++r) {
                hout[(size_t)(prow + r)*160 + t*16 + n] = (acc[t][r] - mu[r])*rs[r]*gm[t] + bt_[t];
            }
        }
    }
}

extern "C" void kernel_launch(void* const* d_in, const int* in_sizes, int n_in,
                              void* d_out, int out_size, void* d_ws, size_t ws_size,
                              hipStream_t stream) {
    const float* X     = (const float*)d_in[0];
    const float* M     = (const float*)d_in[1];
    const float* w_env = (const float*)d_in[2];
    const float* w_bur = (const float*)d_in[3];
    const float* syn   = (const float*)d_in[4];
    const float* wdw   = (const float*)d_in[5];
    const float* wpw   = (const float*)d_in[6];
    const float* wproj = (const float*)d_in[7];
    const float* gam   = (const float*)d_in[8];
    const float* bet   = (const float*)d_in[9];

    float* h      = (float*)d_out;                       // (64,2000,160)
    float* mpatch = h + (size_t)64*2000*160;             // (64,2000)

    __hip_bfloat16* wbf = (__hip_bfloat16*)d_ws;                          // 40 KB
    __hip_bfloat16* xsb = (__hip_bfloat16*)((char*)d_ws + 65536);         // 128000*128*2 = 32.8 MB

    k_cvtw<<<80, 256, 0, stream>>>(wproj, wbf);
    k_pre<<<3200, 256, 0, stream>>>(X, M, w_env, w_bur, syn, wdw, wpw, xsb, mpatch);
    k_proj<<<1000, 256, 0, stream>>>(wbf, xsb, gam, bet, h);
}